// Round 1
// baseline (27.953 us; speedup 1.0000x reference)
//
#include <hip/hip_runtime.h>
#include <math.h>

#define BLOCK 256
#define EPS 1e-5f

// ---------------------------------------------------------------------------
// Per-row kernel: one block per (b, i). Computes
//   lam_i = pref * sum_{j<i, t_j>0} exp(-beta*(t_i-t_j) - ds2*inv2s2) + mu[cls_i]
// and writes log(lam_i + eps) (or 0 if t_i<=0) to row_out[row].
// ---------------------------------------------------------------------------
__global__ void __launch_bounds__(BLOCK)
hawkes_row_kernel(const float* __restrict__ X,
                  const float* __restrict__ mu,
                  const float* __restrict__ alpha_p,
                  const float* __restrict__ beta_p,
                  const float* __restrict__ sigma_p,
                  float* __restrict__ row_out,
                  int L) {
    const int row = blockIdx.x;
    const int b   = row / L;
    const int i   = row - b * L;

    const float4* __restrict__ Xb = reinterpret_cast<const float4*>(X) + (size_t)b * L;
    const float4 xi = Xb[i];
    const float ti   = xi.x;
    const int   ci   = (int)xi.y;
    const float loni = xi.z;
    const float lati = xi.w;

    const float alpha = alpha_p[0];
    const float beta  = beta_p[0];
    const float sigma = sigma_p[0];
    const float two_sig2 = 2.0f * sigma * sigma;
    const float inv2s2   = 1.0f / two_sig2;
    const float pref     = alpha * beta / ((float)M_PI * two_sig2);

    float partial = 0.0f;
    for (int j = threadIdx.x; j < i; j += BLOCK) {
        const float4 xj = Xb[j];
        if (xj.x > 0.0f) {                 // valid[j]
            const float dt   = ti - xj.x;  // >= 0 (t sorted)
            const float dlon = loni - xj.z;
            const float dlat = lati - xj.w;
            const float e = -beta * dt - (dlon * dlon + dlat * dlat) * inv2s2;
            partial += __expf(e);
        }
    }

    // wave (64-lane) butterfly reduce
    #pragma unroll
    for (int off = 32; off > 0; off >>= 1)
        partial += __shfl_down(partial, off, 64);

    __shared__ float smem[BLOCK / 64];
    const int wid  = threadIdx.x >> 6;
    const int lane = threadIdx.x & 63;
    if (lane == 0) smem[wid] = partial;
    __syncthreads();

    if (threadIdx.x == 0) {
        float s = 0.0f;
        #pragma unroll
        for (int w = 0; w < BLOCK / 64; ++w) s += smem[w];
        const float lam = pref * s + mu[ci];
        row_out[row] = (ti > 0.0f) ? logf(lam + EPS) : 0.0f;
    }
}

// Atomic-path variant: adds log term directly into d_out[0].
__global__ void __launch_bounds__(BLOCK)
hawkes_row_atomic_kernel(const float* __restrict__ X,
                         const float* __restrict__ mu,
                         const float* __restrict__ alpha_p,
                         const float* __restrict__ beta_p,
                         const float* __restrict__ sigma_p,
                         float* __restrict__ out,
                         int L) {
    const int row = blockIdx.x;
    const int b   = row / L;
    const int i   = row - b * L;

    const float4* __restrict__ Xb = reinterpret_cast<const float4*>(X) + (size_t)b * L;
    const float4 xi = Xb[i];
    const float ti   = xi.x;
    const int   ci   = (int)xi.y;
    const float loni = xi.z;
    const float lati = xi.w;

    const float alpha = alpha_p[0];
    const float beta  = beta_p[0];
    const float sigma = sigma_p[0];
    const float two_sig2 = 2.0f * sigma * sigma;
    const float inv2s2   = 1.0f / two_sig2;
    const float pref     = alpha * beta / ((float)M_PI * two_sig2);

    float partial = 0.0f;
    for (int j = threadIdx.x; j < i; j += BLOCK) {
        const float4 xj = Xb[j];
        if (xj.x > 0.0f) {
            const float dt   = ti - xj.x;
            const float dlon = loni - xj.z;
            const float dlat = lati - xj.w;
            const float e = -beta * dt - (dlon * dlon + dlat * dlat) * inv2s2;
            partial += __expf(e);
        }
    }
    #pragma unroll
    for (int off = 32; off > 0; off >>= 1)
        partial += __shfl_down(partial, off, 64);

    __shared__ float smem[BLOCK / 64];
    const int wid  = threadIdx.x >> 6;
    const int lane = threadIdx.x & 63;
    if (lane == 0) smem[wid] = partial;
    __syncthreads();

    if (threadIdx.x == 0) {
        float s = 0.0f;
        #pragma unroll
        for (int w = 0; w < BLOCK / 64; ++w) s += smem[w];
        const float lam = pref * s + mu[ci];
        if (ti > 0.0f) atomicAdd(out, logf(lam + EPS));
    }
}

// Init kernel for atomic path: out[0] = -baserate
__global__ void init_out_kernel(const float* __restrict__ mu,
                                float* __restrict__ out, int B) {
    if (threadIdx.x == 0 && blockIdx.x == 0) {
        const double area = ((-0.3) - (-0.42)) * (111.32 * 0.772)
                          * ((39.52) - (39.4)) * 110.574;
        const float summu = mu[0] + mu[1] + mu[2] + mu[3];
        out[0] = -(summu * 365.0f * (float)area * (float)B);
    }
}

// Final deterministic reduce: out[0] = sum(row_vals) - baserate
__global__ void __launch_bounds__(BLOCK)
hawkes_reduce_kernel(const float* __restrict__ row_vals,
                     const float* __restrict__ mu,
                     float* __restrict__ out,
                     int n, int B) {
    float partial = 0.0f;
    for (int idx = threadIdx.x; idx < n; idx += BLOCK)
        partial += row_vals[idx];

    #pragma unroll
    for (int off = 32; off > 0; off >>= 1)
        partial += __shfl_down(partial, off, 64);

    __shared__ float smem[BLOCK / 64];
    const int wid  = threadIdx.x >> 6;
    const int lane = threadIdx.x & 63;
    if (lane == 0) smem[wid] = partial;
    __syncthreads();

    if (threadIdx.x == 0) {
        float s = 0.0f;
        #pragma unroll
        for (int w = 0; w < BLOCK / 64; ++w) s += smem[w];
        const double area = ((-0.3) - (-0.42)) * (111.32 * 0.772)
                          * ((39.52) - (39.4)) * 110.574;
        const float summu = mu[0] + mu[1] + mu[2] + mu[3];
        const float baserate = summu * 365.0f * (float)area * (float)B;
        out[0] = s - baserate;
    }
}

extern "C" void kernel_launch(void* const* d_in, const int* in_sizes, int n_in,
                              void* d_out, int out_size, void* d_ws, size_t ws_size,
                              hipStream_t stream) {
    const float* X     = (const float*)d_in[0];
    const float* mu    = (const float*)d_in[1];
    const float* alpha = (const float*)d_in[2];
    const float* beta  = (const float*)d_in[3];
    const float* sigma = (const float*)d_in[4];
    float* out = (float*)d_out;

    const int BL = in_sizes[0] / 4;  // B * L (X has 4 features)
    const int L  = 2048;             // fixed by the reference setup
    const int B  = BL / L;

    if (ws_size >= (size_t)BL * sizeof(float)) {
        // deterministic path: per-row values -> single-block reduce
        float* rows = (float*)d_ws;
        hawkes_row_kernel<<<BL, BLOCK, 0, stream>>>(X, mu, alpha, beta, sigma, rows, L);
        hawkes_reduce_kernel<<<1, BLOCK, 0, stream>>>(rows, mu, out, BL, B);
    } else {
        // fallback: atomic accumulation
        init_out_kernel<<<1, 64, 0, stream>>>(mu, out, B);
        hawkes_row_atomic_kernel<<<BL, BLOCK, 0, stream>>>(X, mu, alpha, beta, sigma, out, L);
    }
}